// Round 1
// baseline (722.492 us; speedup 1.0000x reference)
//
#include <hip/hip_runtime.h>
#include <hip/hip_bf16.h>
#include <math.h>

#define B_ 64
#define N_ 197
#define C_ 768
#define H_ 12
#define BN_ (B_ * N_)   // 12608
#define MPAD 12672      // workspace row padding (99*128)

typedef unsigned short ushort_t;
typedef __attribute__((ext_vector_type(8))) short short8;   // 8 x bf16 (4 VGPRs)
typedef __attribute__((ext_vector_type(4))) float f32x4;    // MFMA C/D frag

__device__ __forceinline__ float wave_reduce_sum(float v) {
#pragma unroll
  for (int off = 32; off; off >>= 1) v += __shfl_xor(v, off);
  return v;
}

__device__ __forceinline__ ushort_t f2bf(float f) {
  __hip_bfloat16 h = __float2bfloat16(f);
  ushort_t u;
  __builtin_memcpy(&u, &h, 2);
  return u;
}

__device__ __forceinline__ float gelu_fast(float u) {
  // tanh-form GELU via hw exp; max abs err ~3e-4 (<< 0.116 tolerance)
  const float z2 = 1.5957691216f * (u + 0.044715f * u * u * u);
  const float e = __expf(z2);
  const float th = 1.f - 2.f / (e + 1.f);
  return 0.5f * u * (1.f + th);
}

// ---------------- weight convert + transpose: fp32 [K][N] -> bf16 [N][K] -----
__global__ __launch_bounds__(256) void wtrans_kernel(const float* __restrict__ W,
                                                     ushort_t* __restrict__ Wt,
                                                     int K, int N) {
  __shared__ ushort_t tile[32][33];
  const int bn = blockIdx.x * 32, bk = blockIdx.y * 32;
  const int tx = threadIdx.x & 31, ty = threadIdx.x >> 5;  // 32 x 8
#pragma unroll
  for (int i = ty; i < 32; i += 8)
    tile[i][tx] = f2bf(W[(size_t)(bk + i) * N + bn + tx]);
  __syncthreads();
#pragma unroll
  for (int i = ty; i < 32; i += 8)
    Wt[(size_t)(bn + i) * K + bk + tx] = tile[tx][i];
}

// ---------------- LayerNorm -> bf16 out --------------------------------------
__global__ __launch_bounds__(256) void ln_kernel(const float* __restrict__ x,
                                                 const float* __restrict__ w,
                                                 const float* __restrict__ bsh,
                                                 ushort_t* __restrict__ out) {
  const int row = blockIdx.x;
  const float* xr = x + (size_t)row * C_;
  const int tid = threadIdx.x;
  float v0 = xr[tid], v1 = xr[tid + 256], v2 = xr[tid + 512];
  float s = v0 + v1 + v2;
  float q = v0 * v0 + v1 * v1 + v2 * v2;
  s = wave_reduce_sum(s);
  q = wave_reduce_sum(q);
  __shared__ float red[8];
  const int w4 = tid >> 6, l = tid & 63;
  if (l == 0) { red[w4] = s; red[4 + w4] = q; }
  __syncthreads();
  float ts = red[0] + red[1] + red[2] + red[3];
  float tq = red[4] + red[5] + red[6] + red[7];
  float mu = ts * (1.f / C_);
  float var = tq * (1.f / C_) - mu * mu;
  float rs = rsqrtf(var + 1e-5f);
  ushort_t* orow = out + (size_t)row * C_;
  orow[tid]       = f2bf((v0 - mu) * rs * w[tid]       + bsh[tid]);
  orow[tid + 256] = f2bf((v1 - mu) * rs * w[tid + 256] + bsh[tid + 256]);
  orow[tid + 512] = f2bf((v2 - mu) * rs * w[tid + 512] + bsh[tid + 512]);
}

// ---------------- bf16 MFMA GEMM, 256-wide tile, 4-deep ring pipeline --------
// BM=256, BN_T in {256,128}, BK=32, 512 threads (8 waves), 16x16x32 MFMA.
// Ring of 4 LDS slots; iteration it computes slot it&3 and stages tile it+3
// into slot (it+3)&3 == (it-1)&3 (readers passed this iteration's barrier).
// Counted s_waitcnt vmcnt(2*LPI) before the barrier -- never drained to 0 in
// the main loop (T3+T4). XOR k-octet swizzle identical to the verified r6/r7
// layout (0 bank conflicts). Per-barrier MFMA work = 256 mfma (CU ~1242 cyc),
// stage->consume lookahead = 3 iterations, so HBM latency is covered.
template <int BN_T, int RES, int ACT, int OUT_BF16>
__global__ __launch_bounds__(512, 2) void mfma_gemm2(const ushort_t* __restrict__ A,
                                                     const ushort_t* __restrict__ Bt,
                                                     const float* __restrict__ bias,
                                                     const float* __restrict__ res,
                                                     void* __restrict__ Cout,
                                                     int M, int Nc, int K, int gridN) {
  __shared__ __align__(16) ushort_t As[4][256][32];
  __shared__ __align__(16) ushort_t Bs[4][BN_T][32];

  // XCD swizzle: flat%8 = XCD (round-robin dispatch); n fastest within m-group.
  const int flat = blockIdx.x;
  const int x8 = flat & 7, q8 = flat >> 3;
  const int n_t = q8 % gridN, jj = q8 / gridN;
  const int m_t = jj * 8 + x8;
  const int gridM = (M + 255) >> 8;
  if (m_t >= gridM) return;  // block-uniform early exit (pad blocks)

  const int tid = threadIdx.x;
  const int w = tid >> 6, l = tid & 63;
  const int quad = l >> 4, lm = l & 15;
  const int bm = m_t * 256, bnn = n_t * BN_T;

  constexpr int MR = (BN_T == 256) ? 8 : 4;   // 16-row frags per wave (M)
  constexpr int NR = 4;                       // 16-col frags per wave (N)
  constexpr int LPI = (BN_T == 256) ? 4 : 3;  // global_load_lds per thread/iter
  constexpr int VMC = 2 * LPI;                // counted vmcnt (2 tiles in flight)
  const int wm = (BN_T == 256) ? (w >> 2) * 128 : (w >> 1) * 64;
  const int wn = (BN_T == 256) ? (w & 3) * 64 : (w & 1) * 64;

  // Staging map (identical swizzle relation to r6/r7): lane l covers
  // row = base + (l>>2), source k-octet = (l&3) ^ ((l>>3)&3).
  const int srow = l >> 2;
  const int scol = ((l & 3) ^ ((l >> 3) & 3)) << 3;
  int ar0 = bm + w * 32 + srow;      if (ar0 >= MPAD) ar0 = 0;  // clamp last M-tile
  int ar1 = bm + w * 32 + 16 + srow; if (ar1 >= MPAD) ar1 = 0;
  const ushort_t* ag0 = A + (size_t)ar0 * K + scol;
  const ushort_t* ag1 = A + (size_t)ar1 * K + scol;
  const int brow0 = bnn + ((BN_T == 256) ? w * 32 : w * 16) + srow;
  const ushort_t* bg0 = Bt + (size_t)brow0 * K + scol;
  const ushort_t* bg1 = Bt + (size_t)(bnn + w * 32 + 16 + srow) * K + scol;  // BN_T==256 only

  auto stage = [&](int slot, int tile) {
    const int k0 = tile << 5;
    __builtin_amdgcn_global_load_lds(
        (const __attribute__((address_space(1))) void*)(ag0 + k0),
        (__attribute__((address_space(3))) void*)&As[slot][w * 32][0], 16, 0, 0);
    __builtin_amdgcn_global_load_lds(
        (const __attribute__((address_space(1))) void*)(ag1 + k0),
        (__attribute__((address_space(3))) void*)&As[slot][w * 32 + 16][0], 16, 0, 0);
    if constexpr (BN_T == 256) {
      __builtin_amdgcn_global_load_lds(
          (const __attribute__((address_space(1))) void*)(bg0 + k0),
          (__attribute__((address_space(3))) void*)&Bs[slot][w * 32][0], 16, 0, 0);
      __builtin_amdgcn_global_load_lds(
          (const __attribute__((address_space(1))) void*)(bg1 + k0),
          (__attribute__((address_space(3))) void*)&Bs[slot][w * 32 + 16][0], 16, 0, 0);
    } else {
      __builtin_amdgcn_global_load_lds(
          (const __attribute__((address_space(1))) void*)(bg0 + k0),
          (__attribute__((address_space(3))) void*)&Bs[slot][w * 16][0], 16, 0, 0);
    }
  };

  const int fslot = (quad ^ ((lm >> 1) & 3)) << 3;  // frag read k-octet (swizzled)

  f32x4 acc[MR][NR];
#pragma unroll
  for (int mi = 0; mi < MR; mi++)
#pragma unroll
    for (int ni = 0; ni < NR; ni++) acc[mi][ni] = (f32x4){0.f, 0.f, 0.f, 0.f};

  const int NIT = K >> 5;  // 24 (K=768) or 96 (K=3072); always >= 3
  stage(0, 0);
  stage(1, 1);
  stage(2, 2);
  for (int it = 0; it < NIT; ++it) {
    const int slot = it & 3;
    // my stage for slot `it` (issued at it-3) must be done; allow the 2 newer
    // tiles (it+1, it+2) to stay in flight. Barrier then makes ALL waves'
    // stages for this slot visible.
    asm volatile("s_waitcnt vmcnt(%0)" ::"n"(VMC) : "memory");
    __builtin_amdgcn_s_barrier();
    asm volatile("" ::: "memory");  // keep ds_reads below the barrier
    if (it + 3 < NIT) stage((it + 3) & 3, it + 3);  // writes slot (it-1)&3: free

    short8 af[MR], bfr[NR];
#pragma unroll
    for (int i = 0; i < MR; i++)
      af[i] = *(const short8*)&As[slot][wm + i * 16 + lm][fslot];
#pragma unroll
    for (int n = 0; n < NR; n++)
      bfr[n] = *(const short8*)&Bs[slot][wn + n * 16 + lm][fslot];
#pragma unroll
    for (int mi = 0; mi < MR; mi++)
#pragma unroll
      for (int ni = 0; ni < NR; ni++)
        acc[mi][ni] = __builtin_amdgcn_mfma_f32_16x16x32_bf16(af[mi], bfr[ni],
                                                              acc[mi][ni], 0, 0, 0);
  }

  // Epilogue: C/D layout col=lane&15, row=quad*4+reg (verified).
#pragma unroll
  for (int mi = 0; mi < MR; mi++) {
#pragma unroll
    for (int ni = 0; ni < NR; ni++) {
      const int col = bnn + wn + ni * 16 + lm;
      const float bv = bias[col];
#pragma unroll
      for (int r = 0; r < 4; r++) {
        const int row = bm + wm + mi * 16 + quad * 4 + r;
        if (row < M) {
          float v = acc[mi][ni][r] + bv;
          if constexpr (RES) v += res[(size_t)row * Nc + col];
          if constexpr (ACT) v = gelu_fast(v);
          if constexpr (OUT_BF16)
            ((ushort_t*)Cout)[(size_t)row * Nc + col] = f2bf(v);
          else
            ((float*)Cout)[(size_t)row * Nc + col] = v;
        }
      }
    }
  }
}

// ---------------- MFMA attention: one block per (b,h) ------------------------
__global__ __launch_bounds__(256, 2) void attn_mfma(const ushort_t* __restrict__ qkv,
                                                    const float* __restrict__ mask,
                                                    ushort_t* __restrict__ aout,
                                                    float* __restrict__ imp) {
  __shared__ __align__(16) ushort_t Ks[208 * 64];     // (j, g^(j&7)) swizzle
  __shared__ __align__(16) ushort_t Vt[64 * 216];     // [d][j]
  __shared__ __align__(16) ushort_t Pb[4][16 * 208];  // per-wave P strip
  const int b = blockIdx.x / H_, h = blockIdx.x % H_;
  const int tid = threadIdx.x, w = tid >> 6, l = tid & 63;
  const int quad = l >> 4, lm = l & 15;
  const ushort_t* qbase = qkv + (size_t)b * N_ * 2304 + h * 64;
  const ushort_t* kbase = qbase + 768;
  const ushort_t* vbase = qbase + 1536;

  for (int idx = tid; idx < 208 * 8; idx += 256) {
    const int j = idx >> 3, g = idx & 7;
    uint4 val = make_uint4(0u, 0u, 0u, 0u);
    if (j < N_) val = *(const uint4*)(kbase + (size_t)j * 2304 + g * 8);
    *(uint4*)&Ks[j * 64 + ((g ^ (j & 7)) << 3)] = val;
  }
  for (int idx = tid; idx < 52 * 64; idx += 256) {
    const int d = idx & 63, jg = idx >> 6, j0 = jg * 4;
    ushort_t a0 = 0, a1 = 0, a2 = 0, a3 = 0;
    if (j0 + 0 < N_) a0 = vbase[(size_t)(j0 + 0) * 2304 + d];
    if (j0 + 1 < N_) a1 = vbase[(size_t)(j0 + 1) * 2304 + d];
    if (j0 + 2 < N_) a2 = vbase[(size_t)(j0 + 2) * 2304 + d];
    if (j0 + 3 < N_) a3 = vbase[(size_t)(j0 + 3) * 2304 + d];
    uint2 pk;
    pk.x = (unsigned)a0 | ((unsigned)a1 << 16);
    pk.y = (unsigned)a2 | ((unsigned)a3 << 16);
    *(uint2*)&Vt[d * 216 + j0] = pk;
  }
  float mkv[13];
#pragma unroll
  for (int t = 0; t < 13; t++) {
    const int col = t * 16 + lm;
    mkv[t] = (col < N_) ? mask[b * N_ + col] : 0.f;
  }
  float cs[13];
#pragma unroll
  for (int t = 0; t < 13; t++) cs[t] = 0.f;
  __syncthreads();

  ushort_t* pw = &Pb[w][0];
  for (int i0 = w * 16; i0 < 208; i0 += 64) {
    f32x4 accs[13];
#pragma unroll
    for (int t = 0; t < 13; t++) accs[t] = (f32x4){0.f, 0.f, 0.f, 0.f};
#pragma unroll
    for (int kh = 0; kh < 2; kh++) {
      const int k0 = kh * 32;
      const short8 aq =
          *(const short8*)(qbase + (size_t)(i0 + lm) * 2304 + k0 + quad * 8);
      const int gb = (k0 >> 3) + quad;
#pragma unroll
      for (int t = 0; t < 13; t++) {
        const int j = t * 16 + lm;
        const short8 bk = *(const short8*)&Ks[j * 64 + ((gb ^ (j & 7)) << 3)];
        accs[t] = __builtin_amdgcn_mfma_f32_16x16x32_bf16(aq, bk, accs[t], 0, 0, 0);
      }
    }
    float inv[4];
#pragma unroll
    for (int r = 0; r < 4; r++) {
      float m = -3.4e38f;
#pragma unroll
      for (int t = 0; t < 13; t++) m = fmaxf(m, accs[t][r] * 0.125f);
      m = fmaxf(m, __shfl_xor(m, 1));
      m = fmaxf(m, __shfl_xor(m, 2));
      m = fmaxf(m, __shfl_xor(m, 4));
      m = fmaxf(m, __shfl_xor(m, 8));
      float s = 0.f;
#pragma unroll
      for (int t = 0; t < 13; t++) {
        const float e = __expf(accs[t][r] * 0.125f - m) * mkv[t];
        accs[t][r] = e;
        s += e;
      }
      s += __shfl_xor(s, 1);
      s += __shfl_xor(s, 2);
      s += __shfl_xor(s, 4);
      s += __shfl_xor(s, 8);
      inv[r] = 1.f / (s + 1e-6f);
    }
    const int ibase = i0 + quad * 4;
#pragma unroll
    for (int r = 0; r < 4; r++) {
      const bool rok = (ibase + r) < N_;
#pragma unroll
      for (int t = 0; t < 13; t++) {
        const float p = accs[t][r] * inv[r];
        accs[t][r] = p;
        if (rok) cs[t] += p;
        pw[(quad * 4 + r) * 208 + t * 16 + lm] = f2bf(p);
      }
    }
    __builtin_amdgcn_wave_barrier();
    f32x4 acco[4];
#pragma unroll
    for (int n = 0; n < 4; n++) acco[n] = (f32x4){0.f, 0.f, 0.f, 0.f};
#pragma unroll
    for (int ks = 0; ks < 6; ks++) {
      const int k0 = ks * 32;
      const short8 ap = *(const short8*)&pw[lm * 208 + k0 + quad * 8];
#pragma unroll
      for (int n = 0; n < 4; n++) {
        const short8 bv = *(const short8*)&Vt[(n * 16 + lm) * 216 + k0 + quad * 8];
        acco[n] = __builtin_amdgcn_mfma_f32_16x16x32_bf16(ap, bv, acco[n], 0, 0, 0);
      }
    }
    {
      const bool lo = (quad < 2);
      short8 apt = {};
      if (lo) apt = *(const short8*)&pw[lm * 208 + 192 + quad * 8];
#pragma unroll
      for (int n = 0; n < 4; n++) {
        short8 bvt = {};
        if (lo) bvt = *(const short8*)&Vt[(n * 16 + lm) * 216 + 192 + quad * 8];
        acco[n] = __builtin_amdgcn_mfma_f32_16x16x32_bf16(apt, bvt, acco[n], 0, 0, 0);
      }
    }
#pragma unroll
    for (int r = 0; r < 4; r++) {
      const int i = ibase + r;
      if (i < N_) {
#pragma unroll
        for (int n = 0; n < 4; n++)
          aout[(size_t)(b * N_ + i) * C_ + h * 64 + n * 16 + lm] = f2bf(acco[n][r]);
      }
    }
  }
#pragma unroll
  for (int t = 0; t < 13; t++) {
    float v = cs[t];
    v += __shfl_xor(v, 16);
    v += __shfl_xor(v, 32);
    if (l < 16) {
      const int col = t * 16 + l;
      if (col < N_)
        atomicAdd(&imp[b * N_ + col], v * (1.f / (H_ * (float)N_)));
    }
  }
}

// ---------------- mask output ------------------------------------------------
__global__ __launch_bounds__(256) void mask_kernel(const float* __restrict__ imp,
                                                   const float* __restrict__ mask,
                                                   const float* __restrict__ thr,
                                                   float* __restrict__ mask_out) {
  const int i = blockIdx.x * 256 + threadIdx.x;
  if (i >= BN_) return;
  const int n = i % N_;
  const float iv = (n == 0) ? INFINITY : imp[i];
  const float m = mask[i];
  const float nm = (iv > thr[0]) ? 1.f : 0.f;
  mask_out[i] = (m > 0.f) ? nm : m;
}

extern "C" void kernel_launch(void* const* d_in, const int* in_sizes, int n_in,
                              void* d_out, int out_size, void* d_ws, size_t ws_size,
                              hipStream_t stream) {
  const float* x      = (const float*)d_in[0];
  const float* mask   = (const float*)d_in[1];
  const float* ln1_w  = (const float*)d_in[2];
  const float* ln1_b  = (const float*)d_in[3];
  const float* qkv_w  = (const float*)d_in[4];
  const float* qkv_b  = (const float*)d_in[5];
  const float* proj_w = (const float*)d_in[6];
  const float* proj_b = (const float*)d_in[7];
  const float* ln2_w  = (const float*)d_in[8];
  const float* ln2_b  = (const float*)d_in[9];
  const float* fc1_w  = (const float*)d_in[10];
  const float* fc1_b  = (const float*)d_in[11];
  const float* fc2_w  = (const float*)d_in[12];
  const float* fc2_b  = (const float*)d_in[13];
  const float* thr    = (const float*)d_in[14];

  float* out = (float*)d_out;                // x result: BN_*C_ fp32
  float* mask_out = out + (size_t)BN_ * C_;  // then BN_ fp32

  ushort_t* buf0    = (ushort_t*)d_ws;                   // qkv out / fc1 out (aliased)
  ushort_t* hbuf    = buf0 + (size_t)MPAD * 3072;        // LN out
  ushort_t* aoutb   = hbuf + (size_t)MPAD * 768;         // attention out
  ushort_t* qkv_wt  = aoutb + (size_t)MPAD * 768;        // 2304x768
  ushort_t* proj_wt = qkv_wt + (size_t)2304 * 768;       // 768x768
  ushort_t* fc1_wt  = proj_wt + (size_t)768 * 768;       // 3072x768
  ushort_t* fc2_wt  = fc1_wt + (size_t)3072 * 768;       // 768x3072
  float*    impb    = (float*)(fc2_wt + (size_t)768 * 3072);

  hipMemsetAsync(impb, 0, BN_ * sizeof(float), stream);

  wtrans_kernel<<<dim3(2304 / 32, 768 / 32), 256, 0, stream>>>(qkv_w, qkv_wt, 768, 2304);
  wtrans_kernel<<<dim3(768 / 32, 768 / 32), 256, 0, stream>>>(proj_w, proj_wt, 768, 768);
  wtrans_kernel<<<dim3(3072 / 32, 768 / 32), 256, 0, stream>>>(fc1_w, fc1_wt, 768, 3072);
  wtrans_kernel<<<dim3(768 / 32, 3072 / 32), 256, 0, stream>>>(fc2_w, fc2_wt, 3072, 768);

  // 256-row tiles: gridM = ceil(12608/256) = 50 -> pad m-slots to 56 (7*8)
  const int MS2 = 56;

  ln_kernel<<<BN_, 256, 0, stream>>>(x, ln1_w, ln1_b, hbuf);
  mfma_gemm2<256, 0, 0, 1><<<MS2 * 9, 512, 0, stream>>>(
      hbuf, qkv_wt, qkv_b, nullptr, buf0, BN_, 2304, 768, 9);
  attn_mfma<<<B_ * H_, 256, 0, stream>>>(buf0, mask, aoutb, impb);
  mask_kernel<<<(BN_ + 255) / 256, 256, 0, stream>>>(impb, mask, thr, mask_out);
  mfma_gemm2<128, 1, 0, 0><<<MS2 * 6, 512, 0, stream>>>(
      aoutb, proj_wt, proj_b, x, out, BN_, 768, 768, 6);
  ln_kernel<<<BN_, 256, 0, stream>>>(out, ln2_w, ln2_b, hbuf);
  mfma_gemm2<256, 0, 1, 1><<<MS2 * 12, 512, 0, stream>>>(
      hbuf, fc1_wt, fc1_b, nullptr, buf0, BN_, 3072, 768, 12);
  mfma_gemm2<128, 1, 0, 0><<<MS2 * 6, 512, 0, stream>>>(
      buf0, fc2_wt, fc2_b, out, out, BN_, 768, 3072, 6);
}

// Round 2
// 603.265 us; speedup vs baseline: 1.1976x; 1.1976x over previous
//
#include <hip/hip_runtime.h>
#include <hip/hip_bf16.h>
#include <math.h>

#define B_ 64
#define N_ 197
#define C_ 768
#define H_ 12
#define BN_ (B_ * N_)   // 12608
#define MPAD 12672      // 99 * 128 (workspace row padding)
#define GRIDM 99        // M-tiles (128-row)

typedef unsigned short ushort_t;
typedef __attribute__((ext_vector_type(8))) short short8;   // 8 x bf16 (4 VGPRs)
typedef __attribute__((ext_vector_type(4))) float f32x4;    // MFMA C/D frag

__device__ __forceinline__ float wave_reduce_sum(float v) {
#pragma unroll
  for (int off = 32; off; off >>= 1) v += __shfl_xor(v, off);
  return v;
}

__device__ __forceinline__ ushort_t f2bf(float f) {
  __hip_bfloat16 h = __float2bfloat16(f);
  ushort_t u;
  __builtin_memcpy(&u, &h, 2);
  return u;
}

__device__ __forceinline__ float gelu_fast(float u) {
  // tanh-form GELU via hw exp; max abs err ~3e-4 (<< 0.116 tolerance)
  const float z2 = 1.5957691216f * (u + 0.044715f * u * u * u);
  const float e = __expf(z2);
  const float th = 1.f - 2.f / (e + 1.f);
  return 0.5f * u * (1.f + th);
}

// ---------------- weight convert + transpose: fp32 [K][N] -> bf16 [N][K] -----
__global__ __launch_bounds__(256) void wtrans_kernel(const float* __restrict__ W,
                                                     ushort_t* __restrict__ Wt,
                                                     int K, int N) {
  __shared__ ushort_t tile[32][33];
  const int bn = blockIdx.x * 32, bk = blockIdx.y * 32;
  const int tx = threadIdx.x & 31, ty = threadIdx.x >> 5;  // 32 x 8
#pragma unroll
  for (int i = ty; i < 32; i += 8)
    tile[i][tx] = f2bf(W[(size_t)(bk + i) * N + bn + tx]);
  __syncthreads();
#pragma unroll
  for (int i = ty; i < 32; i += 8)
    Wt[(size_t)(bn + i) * K + bk + tx] = tile[tx][i];
}

// ---------------- LayerNorm -> bf16 out --------------------------------------
__global__ __launch_bounds__(256) void ln_kernel(const float* __restrict__ x,
                                                 const float* __restrict__ w,
                                                 const float* __restrict__ bsh,
                                                 ushort_t* __restrict__ out) {
  const int row = blockIdx.x;
  const float* xr = x + (size_t)row * C_;
  const int tid = threadIdx.x;
  float v0 = xr[tid], v1 = xr[tid + 256], v2 = xr[tid + 512];
  float s = v0 + v1 + v2;
  float q = v0 * v0 + v1 * v1 + v2 * v2;
  s = wave_reduce_sum(s);
  q = wave_reduce_sum(q);
  __shared__ float red[8];
  const int w4 = tid >> 6, l = tid & 63;
  if (l == 0) { red[w4] = s; red[4 + w4] = q; }
  __syncthreads();
  float ts = red[0] + red[1] + red[2] + red[3];
  float tq = red[4] + red[5] + red[6] + red[7];
  float mu = ts * (1.f / C_);
  float var = tq * (1.f / C_) - mu * mu;
  float rs = rsqrtf(var + 1e-5f);
  ushort_t* orow = out + (size_t)row * C_;
  orow[tid]       = f2bf((v0 - mu) * rs * w[tid]       + bsh[tid]);
  orow[tid + 256] = f2bf((v1 - mu) * rs * w[tid + 256] + bsh[tid + 256]);
  orow[tid + 512] = f2bf((v2 - mu) * rs * w[tid + 512] + bsh[tid + 512]);
}

// ---------------- bf16 MFMA GEMM: C = A(MxK) * Bt(NxK)^T + bias --------------
// 128x128 tile, BK=32, 4 waves (2x2 of 64x64), 16x16x32 MFMA, LDS XOR swizzle
// (0 bank conflicts, verified r6). r9: ring-4 pipeline over EIGHT separate
// __shared__ arrays (compile-time slot index so LLVM's LDS-DMA alias tracking
// can prove each ds_read doesn't alias the in-flight global_load_lds -> no
// compiler-inserted vmcnt(0) drain). Raw s_barrier + manual counted
// s_waitcnt vmcnt(8) before each barrier (tiles T+1,T+2 stay in flight);
// exact tail counts vmcnt(4)/vmcnt(0) on the last two tiles. LDS = 64 KB
// -> 2 blocks/CU. Lookahead = 3 tiles (~3.7k cyc) >> HBM latency (~900 cyc).
template <int RES, int ACT, int OUT_BF16>
__global__ __launch_bounds__(256) void mfma_gemm(const ushort_t* __restrict__ A,
                                                 const ushort_t* __restrict__ Bt,
                                                 const float* __restrict__ bias,
                                                 const float* __restrict__ res,
                                                 void* __restrict__ Cout,
                                                 int M, int Nc, int K, int gridN) {
  __shared__ __align__(16) ushort_t As0[128][32];
  __shared__ __align__(16) ushort_t As1[128][32];
  __shared__ __align__(16) ushort_t As2[128][32];
  __shared__ __align__(16) ushort_t As3[128][32];
  __shared__ __align__(16) ushort_t Bs0[128][32];
  __shared__ __align__(16) ushort_t Bs1[128][32];
  __shared__ __align__(16) ushort_t Bs2[128][32];
  __shared__ __align__(16) ushort_t Bs3[128][32];

  // XCD swizzle decode: flat = ((jj*gridN + n)<<3) + x, m_tile = jj*8 + x.
  const int flat = blockIdx.x;
  const int x8 = flat & 7, q8 = flat >> 3;
  const int n_t = q8 % gridN, jj = q8 / gridN;
  const int m_t = jj * 8 + x8;
  if (m_t >= GRIDM) return;  // block-uniform early exit (pad blocks)

  const int tid = threadIdx.x;
  const int w = tid >> 6, l = tid & 63;
  const int bm = m_t * 128, bnn = n_t * 128;
  const int quad = l >> 4, lm = l & 15;
  const int wm = (w >> 1) * 64, wn = (w & 1) * 64;

  const int c0 = w * 2, c1 = w * 2 + 1;
  const int srow = l >> 2;
  const int scol = ((l & 3) ^ ((l >> 3) & 3)) << 3;  // swizzled source k-octet
  const ushort_t* ag0 = A + (size_t)(bm + c0 * 16 + srow) * K + scol;
  const ushort_t* ag1 = A + (size_t)(bm + c1 * 16 + srow) * K + scol;
  const ushort_t* bg0 = Bt + (size_t)(bnn + c0 * 16 + srow) * K + scol;
  const ushort_t* bg1 = Bt + (size_t)(bnn + c1 * 16 + srow) * K + scol;

  auto stage = [&](ushort_t (*Ad)[32], ushort_t (*Bd)[32], int k0) {
    __builtin_amdgcn_global_load_lds(
        (const __attribute__((address_space(1))) void*)(ag0 + k0),
        (__attribute__((address_space(3))) void*)&Ad[c0 * 16][0], 16, 0, 0);
    __builtin_amdgcn_global_load_lds(
        (const __attribute__((address_space(1))) void*)(ag1 + k0),
        (__attribute__((address_space(3))) void*)&Ad[c1 * 16][0], 16, 0, 0);
    __builtin_amdgcn_global_load_lds(
        (const __attribute__((address_space(1))) void*)(bg0 + k0),
        (__attribute__((address_space(3))) void*)&Bd[c0 * 16][0], 16, 0, 0);
    __builtin_amdgcn_global_load_lds(
        (const __attribute__((address_space(1))) void*)(bg1 + k0),
        (__attribute__((address_space(3))) void*)&Bd[c1 * 16][0], 16, 0, 0);
  };

  const int fslot = (quad ^ ((lm >> 1) & 3)) << 3;  // frag read slot

  f32x4 acc[4][4];
#pragma unroll
  for (int mi = 0; mi < 4; mi++)
#pragma unroll
    for (int ni = 0; ni < 4; ni++) acc[mi][ni] = (f32x4){0.f, 0.f, 0.f, 0.f};

  const int NIT = K >> 5;  // 24 or 96; always divisible by 4 and >= 8

// One pipeline step for tile in (Ac,Bc): wait own stage retired (counted),
// barrier (all waves' stages for this slot now resident), optionally issue
// the stage for tile `tn` into (An,Bn) -- a slot whose readers all passed
// this barrier -- then compute.
#define GSTEP(Ac, Bc, An, Bn, tn, VMN, DOSTAGE)                         \
  {                                                                     \
    asm volatile("s_waitcnt vmcnt(" #VMN ")" ::: "memory");             \
    __builtin_amdgcn_s_barrier();                                       \
    asm volatile("" ::: "memory");                                      \
    if (DOSTAGE) stage(An, Bn, (tn) << 5);                              \
    short8 af[4], bf[4];                                                \
    _Pragma("unroll") for (int i = 0; i < 4; i++) {                     \
      af[i] = *(const short8*)&Ac[wm + i * 16 + lm][fslot];             \
      bf[i] = *(const short8*)&Bc[wn + i * 16 + lm][fslot];             \
    }                                                                   \
    _Pragma("unroll") for (int mi = 0; mi < 4; mi++)                    \
      _Pragma("unroll") for (int ni = 0; ni < 4; ni++)                  \
        acc[mi][ni] = __builtin_amdgcn_mfma_f32_16x16x32_bf16(          \
            af[mi], bf[ni], acc[mi][ni], 0, 0, 0);                      \
  }

  stage(As0, Bs0, 0);
  stage(As1, Bs1, 1 << 5);
  stage(As2, Bs2, 2 << 5);
  int t = 0;
  for (; t < NIT - 4; t += 4) {
    GSTEP(As0, Bs0, As3, Bs3, t + 3, 8, true);
    GSTEP(As1, Bs1, As0, Bs0, t + 4, 8, true);
    GSTEP(As2, Bs2, As1, Bs1, t + 5, 8, true);
    GSTEP(As3, Bs3, As2, Bs2, t + 6, 8, true);
  }
  // Tail group (t == NIT-4): tiles NIT-4 .. NIT-1; stage count winds down so
  // the waitcnt must too (at T=NIT-2 only 1 newer stage is in flight, etc.).
  GSTEP(As0, Bs0, As3, Bs3, t + 3, 8, true);   // stages tile NIT-1 (the last)
  GSTEP(As1, Bs1, As0, Bs0, 0, 8, false);      // T=NIT-3: 2 newer in flight
  GSTEP(As2, Bs2, As0, Bs0, 0, 4, false);      // T=NIT-2: 1 newer in flight
  GSTEP(As3, Bs3, As0, Bs0, 0, 0, false);      // T=NIT-1: drain
#undef GSTEP

  // Epilogue: C/D layout col=lane&15, row=quad*4+reg.
#pragma unroll
  for (int mi = 0; mi < 4; mi++) {
#pragma unroll
    for (int ni = 0; ni < 4; ni++) {
      const int col = bnn + wn + ni * 16 + lm;
      const float bv = bias[col];
#pragma unroll
      for (int r = 0; r < 4; r++) {
        const int row = bm + wm + mi * 16 + quad * 4 + r;
        if (row < M) {
          float v = acc[mi][ni][r] + bv;
          if constexpr (RES) v += res[(size_t)row * Nc + col];
          if constexpr (ACT) v = gelu_fast(v);
          if constexpr (OUT_BF16)
            ((ushort_t*)Cout)[(size_t)row * Nc + col] = f2bf(v);
          else
            ((float*)Cout)[(size_t)row * Nc + col] = v;
        }
      }
    }
  }
}

// ---------------- MFMA attention: one block per (b,h) ------------------------
__global__ __launch_bounds__(256, 2) void attn_mfma(const ushort_t* __restrict__ qkv,
                                                    const float* __restrict__ mask,
                                                    ushort_t* __restrict__ aout,
                                                    float* __restrict__ imp) {
  __shared__ __align__(16) ushort_t Ks[208 * 64];     // (j, g^(j&7)) swizzle
  __shared__ __align__(16) ushort_t Vt[64 * 216];     // [d][j]
  __shared__ __align__(16) ushort_t Pb[4][16 * 208];  // per-wave P strip
  const int b = blockIdx.x / H_, h = blockIdx.x % H_;
  const int tid = threadIdx.x, w = tid >> 6, l = tid & 63;
  const int quad = l >> 4, lm = l & 15;
  const ushort_t* qbase = qkv + (size_t)b * N_ * 2304 + h * 64;
  const ushort_t* kbase = qbase + 768;
  const ushort_t* vbase = qbase + 1536;

  for (int idx = tid; idx < 208 * 8; idx += 256) {
    const int j = idx >> 3, g = idx & 7;
    uint4 val = make_uint4(0u, 0u, 0u, 0u);
    if (j < N_) val = *(const uint4*)(kbase + (size_t)j * 2304 + g * 8);
    *(uint4*)&Ks[j * 64 + ((g ^ (j & 7)) << 3)] = val;
  }
  for (int idx = tid; idx < 52 * 64; idx += 256) {
    const int d = idx & 63, jg = idx >> 6, j0 = jg * 4;
    ushort_t a0 = 0, a1 = 0, a2 = 0, a3 = 0;
    if (j0 + 0 < N_) a0 = vbase[(size_t)(j0 + 0) * 2304 + d];
    if (j0 + 1 < N_) a1 = vbase[(size_t)(j0 + 1) * 2304 + d];
    if (j0 + 2 < N_) a2 = vbase[(size_t)(j0 + 2) * 2304 + d];
    if (j0 + 3 < N_) a3 = vbase[(size_t)(j0 + 3) * 2304 + d];
    uint2 pk;
    pk.x = (unsigned)a0 | ((unsigned)a1 << 16);
    pk.y = (unsigned)a2 | ((unsigned)a3 << 16);
    *(uint2*)&Vt[d * 216 + j0] = pk;
  }
  float mkv[13];
#pragma unroll
  for (int t = 0; t < 13; t++) {
    const int col = t * 16 + lm;
    mkv[t] = (col < N_) ? mask[b * N_ + col] : 0.f;
  }
  float cs[13];
#pragma unroll
  for (int t = 0; t < 13; t++) cs[t] = 0.f;
  __syncthreads();

  ushort_t* pw = &Pb[w][0];
  for (int i0 = w * 16; i0 < 208; i0 += 64) {
    f32x4 accs[13];
#pragma unroll
    for (int t = 0; t < 13; t++) accs[t] = (f32x4){0.f, 0.f, 0.f, 0.f};
#pragma unroll
    for (int kh = 0; kh < 2; kh++) {
      const int k0 = kh * 32;
      const short8 aq =
          *(const short8*)(qbase + (size_t)(i0 + lm) * 2304 + k0 + quad * 8);
      const int gb = (k0 >> 3) + quad;
#pragma unroll
      for (int t = 0; t < 13; t++) {
        const int j = t * 16 + lm;
        const short8 bk = *(const short8*)&Ks[j * 64 + ((gb ^ (j & 7)) << 3)];
        accs[t] = __builtin_amdgcn_mfma_f32_16x16x32_bf16(aq, bk, accs[t], 0, 0, 0);
      }
    }
    float inv[4];
#pragma unroll
    for (int r = 0; r < 4; r++) {
      float m = -3.4e38f;
#pragma unroll
      for (int t = 0; t < 13; t++) m = fmaxf(m, accs[t][r] * 0.125f);
      m = fmaxf(m, __shfl_xor(m, 1));
      m = fmaxf(m, __shfl_xor(m, 2));
      m = fmaxf(m, __shfl_xor(m, 4));
      m = fmaxf(m, __shfl_xor(m, 8));
      float s = 0.f;
#pragma unroll
      for (int t = 0; t < 13; t++) {
        const float e = __expf(accs[t][r] * 0.125f - m) * mkv[t];
        accs[t][r] = e;
        s += e;
      }
      s += __shfl_xor(s, 1);
      s += __shfl_xor(s, 2);
      s += __shfl_xor(s, 4);
      s += __shfl_xor(s, 8);
      inv[r] = 1.f / (s + 1e-6f);
    }
    const int ibase = i0 + quad * 4;
#pragma unroll
    for (int r = 0; r < 4; r++) {
      const bool rok = (ibase + r) < N_;
#pragma unroll
      for (int t = 0; t < 13; t++) {
        const float p = accs[t][r] * inv[r];
        accs[t][r] = p;
        if (rok) cs[t] += p;
        pw[(quad * 4 + r) * 208 + t * 16 + lm] = f2bf(p);
      }
    }
    __builtin_amdgcn_wave_barrier();
    f32x4 acco[4];
#pragma unroll
    for (int n = 0; n < 4; n++) acco[n] = (f32x4){0.f, 0.f, 0.f, 0.f};
#pragma unroll
    for (int ks = 0; ks < 6; ks++) {
      const int k0 = ks * 32;
      const short8 ap = *(const short8*)&pw[lm * 208 + k0 + quad * 8];
#pragma unroll
      for (int n = 0; n < 4; n++) {
        const short8 bv = *(const short8*)&Vt[(n * 16 + lm) * 216 + k0 + quad * 8];
        acco[n] = __builtin_amdgcn_mfma_f32_16x16x32_bf16(ap, bv, acco[n], 0, 0, 0);
      }
    }
    {
      const bool lo = (quad < 2);
      short8 apt = {};
      if (lo) apt = *(const short8*)&pw[lm * 208 + 192 + quad * 8];
#pragma unroll
      for (int n = 0; n < 4; n++) {
        short8 bvt = {};
        if (lo) bvt = *(const short8*)&Vt[(n * 16 + lm) * 216 + 192 + quad * 8];
        acco[n] = __builtin_amdgcn_mfma_f32_16x16x32_bf16(apt, bvt, acco[n], 0, 0, 0);
      }
    }
#pragma unroll
    for (int r = 0; r < 4; r++) {
      const int i = ibase + r;
      if (i < N_) {
#pragma unroll
        for (int n = 0; n < 4; n++)
          aout[(size_t)(b * N_ + i) * C_ + h * 64 + n * 16 + lm] = f2bf(acco[n][r]);
      }
    }
  }
#pragma unroll
  for (int t = 0; t < 13; t++) {
    float v = cs[t];
    v += __shfl_xor(v, 16);
    v += __shfl_xor(v, 32);
    if (l < 16) {
      const int col = t * 16 + l;
      if (col < N_)
        atomicAdd(&imp[b * N_ + col], v * (1.f / (H_ * (float)N_)));
    }
  }
}

// ---------------- mask output ------------------------------------------------
__global__ __launch_bounds__(256) void mask_kernel(const float* __restrict__ imp,
                                                   const float* __restrict__ mask,
                                                   const float* __restrict__ thr,
                                                   float* __restrict__ mask_out) {
  const int i = blockIdx.x * 256 + threadIdx.x;
  if (i >= BN_) return;
  const int n = i % N_;
  const float iv = (n == 0) ? INFINITY : imp[i];
  const float m = mask[i];
  const float nm = (iv > thr[0]) ? 1.f : 0.f;
  mask_out[i] = (m > 0.f) ? nm : m;
}

extern "C" void kernel_launch(void* const* d_in, const int* in_sizes, int n_in,
                              void* d_out, int out_size, void* d_ws, size_t ws_size,
                              hipStream_t stream) {
  const float* x      = (const float*)d_in[0];
  const float* mask   = (const float*)d_in[1];
  const float* ln1_w  = (const float*)d_in[2];
  const float* ln1_b  = (const float*)d_in[3];
  const float* qkv_w  = (const float*)d_in[4];
  const float* qkv_b  = (const float*)d_in[5];
  const float* proj_w = (const float*)d_in[6];
  const float* proj_b = (const float*)d_in[7];
  const float* ln2_w  = (const float*)d_in[8];
  const float* ln2_b  = (const float*)d_in[9];
  const float* fc1_w  = (const float*)d_in[10];
  const float* fc1_b  = (const float*)d_in[11];
  const float* fc2_w  = (const float*)d_in[12];
  const float* fc2_b  = (const float*)d_in[13];
  const float* thr    = (const float*)d_in[14];

  float* out = (float*)d_out;                // x result: BN_*C_ fp32
  float* mask_out = out + (size_t)BN_ * C_;  // then BN_ fp32

  ushort_t* buf0    = (ushort_t*)d_ws;                   // qkv out / fc1 out (aliased)
  ushort_t* hbuf    = buf0 + (size_t)MPAD * 3072;        // LN out
  ushort_t* aoutb   = hbuf + (size_t)MPAD * 768;         // attention out
  ushort_t* qkv_wt  = aoutb + (size_t)MPAD * 768;        // 2304x768
  ushort_t* proj_wt = qkv_wt + (size_t)2304 * 768;       // 768x768
  ushort_t* fc1_wt  = proj_wt + (size_t)768 * 768;       // 3072x768
  ushort_t* fc2_wt  = fc1_wt + (size_t)3072 * 768;       // 768x3072
  float*    impb    = (float*)(fc2_wt + (size_t)768 * 3072);

  hipMemsetAsync(impb, 0, BN_ * sizeof(float), stream);

  wtrans_kernel<<<dim3(2304 / 32, 768 / 32), 256, 0, stream>>>(qkv_w, qkv_wt, 768, 2304);
  wtrans_kernel<<<dim3(768 / 32, 768 / 32), 256, 0, stream>>>(proj_w, proj_wt, 768, 768);
  wtrans_kernel<<<dim3(3072 / 32, 768 / 32), 256, 0, stream>>>(fc1_w, fc1_wt, 768, 3072);
  wtrans_kernel<<<dim3(768 / 32, 3072 / 32), 256, 0, stream>>>(fc2_w, fc2_wt, 3072, 768);

  // swizzled 1D grids: ceil(GRIDM/8)=13 m-slot groups -> grid = 104 * gridN
  const int MS = 13 * 8;  // 104
  ln_kernel<<<BN_, 256, 0, stream>>>(x, ln1_w, ln1_b, hbuf);
  mfma_gemm<0, 0, 1><<<MS * 18, 256, 0, stream>>>(
      hbuf, qkv_wt, qkv_b, nullptr, buf0, BN_, 2304, 768, 18);
  attn_mfma<<<B_ * H_, 256, 0, stream>>>(buf0, mask, aoutb, impb);
  mask_kernel<<<(BN_ + 255) / 256, 256, 0, stream>>>(impb, mask, thr, mask_out);
  mfma_gemm<1, 0, 0><<<MS * 6, 256, 0, stream>>>(
      aoutb, proj_wt, proj_b, x, out, BN_, 768, 768, 6);
  ln_kernel<<<BN_, 256, 0, stream>>>(out, ln2_w, ln2_b, hbuf);
  mfma_gemm<0, 1, 1><<<MS * 24, 256, 0, stream>>>(
      hbuf, fc1_wt, fc1_b, nullptr, buf0, BN_, 3072, 768, 24);
  mfma_gemm<1, 0, 0><<<MS * 6, 256, 0, stream>>>(
      buf0, fc2_wt, fc2_b, out, out, BN_, 768, 3072, 6);
}